// Round 5
// baseline (3789.775 us; speedup 1.0000x reference)
//
#include <hip/hip_runtime.h>
#include <stdint.h>

#define TAGS 29
#define START_TAG 27
#define STOP_TAG 28
#define BB 64
#define LL 1024
#define DD 1024
#define HH 512
#define FSTRIDE 32   // padded feats row stride (floats)

typedef float f2 __attribute__((ext_vector_type(2)));

// ---------------------------------------------------------------------------
// XLA EmitFastTanh clone, f32, with_fma=false (CPU elemental emitter config):
// separate mul/add roundings, clamp +-7.90531110763549805, P13/Q6 Horner,
// |x|<4e-4 -> x. contract(off) inside the body.
// ---------------------------------------------------------------------------
__device__ __forceinline__ float xla_tanh_f32(float x) {
#pragma clang fp contract(off)
  const float kMax = 7.90531110763549805f;
  float xc = fminf(fmaxf(x, -kMax), kMax);
  float x2 = xc * xc;
  float p = x2 * -2.76076847742355e-16f + 2.00018790482477e-13f;
  p = x2 * p + -8.60467152213735e-11f;
  p = x2 * p + 5.12229709037114e-08f;
  p = x2 * p + 1.48572235717979e-05f;
  p = x2 * p + 6.37261928875436e-04f;
  p = x2 * p + 4.89352455891786e-03f;
  p = xc * p;
  float q = x2 * 1.19825839466702e-06f + 1.18534705686654e-04f;
  q = x2 * q + 2.26843463243900e-03f;
  q = x2 * q + 4.89352518554385e-03f;
  float r = p / q;                       // IEEE div
  return (fabsf(x) < 4.0e-4f) ? x : r;
}

// ---------------------------------------------------------------------------
// Kernel 1: fused MLP  feats = tanh(X@W1 + b1) @ W2 + b2
// 512 threads / 64 rows x 512 hidden cols per block.
// - contract(off): Eigen (AVX, no FMA) = sequential-k mul-then-add chain.
// - packed f32 (float2) math: v_pk_mul/v_pk_add, bit-identical, half the issue.
// - thread cols {4cg..+3} u {256+4cg..+3}: wl reads are contiguous b128 (no
//   bank conflicts); xs stride 65 (2-way max on writes, broadcast reads).
// - LDS 73.8 KB union (staging | 64x260 half-h) -> 2 blocks/CU.
// ---------------------------------------------------------------------------
__global__ __launch_bounds__(512, 4) void mlp_kernel(
    const float* __restrict__ X, const float* __restrict__ W1,
    const float* __restrict__ b1, const float* __restrict__ W2,
    const float* __restrict__ b2, float* __restrict__ feats)
{
#pragma clang fp contract(off)
  __shared__ __align__(16) float smem[18464];   // 73856 B
  float* xs = smem;               // [32][65]  k-major X tile
  float* wl = smem + 32 * 65;     // [32][512] W1 tile
  float* hs = smem;               // [64][260] half of h (reused)

  const int tid  = threadIdx.x;
  const int row0 = blockIdx.x * 64;
  const int rg = tid >> 6, cg = tid & 63;      // 8 row-groups x 64 col-groups
  const int xr = tid >> 3, xk4 = tid & 7;      // X loader
  const int wc4 = tid & 127, wk0 = tid >> 7;   // W loader

  f2 acc[8][4];                                // rows x {2+2 | 2+2} packed cols
#pragma unroll
  for (int i = 0; i < 8; ++i)
#pragma unroll
    for (int j = 0; j < 4; ++j) acc[i][j] = (f2)(0.f);

  float4 xv = *(const float4*)(X + (size_t)(row0 + xr) * DD + xk4 * 4);
  float4 wv[8];
#pragma unroll
  for (int j = 0; j < 8; ++j)
    wv[j] = *(const float4*)(W1 + (size_t)(wk0 + j * 4) * HH + wc4 * 4);

  for (int kb = 0; kb < DD; kb += 32) {
    __syncthreads();
    xs[(xk4 * 4 + 0) * 65 + xr] = xv.x;
    xs[(xk4 * 4 + 1) * 65 + xr] = xv.y;
    xs[(xk4 * 4 + 2) * 65 + xr] = xv.z;
    xs[(xk4 * 4 + 3) * 65 + xr] = xv.w;
#pragma unroll
    for (int j = 0; j < 8; ++j)
      *(float4*)(wl + (wk0 + j * 4) * HH + wc4 * 4) = wv[j];
    __syncthreads();
    if (kb + 32 < DD) {
      xv = *(const float4*)(X + (size_t)(row0 + xr) * DD + (kb + 32) + xk4 * 4);
#pragma unroll
      for (int j = 0; j < 8; ++j)
        wv[j] = *(const float4*)(W1 + (size_t)(kb + 32 + wk0 + j * 4) * HH + wc4 * 4);
    }
#pragma unroll 4
    for (int k = 0; k < 32; ++k) {
      float4 a0 = *(float4*)(xs + k * 65 + rg * 8);        // broadcast (uniform)
      float4 a1 = *(float4*)(xs + k * 65 + rg * 8 + 4);
      float4 b0 = *(float4*)(wl + k * HH + cg * 4);        // contiguous b128
      float4 b1v = *(float4*)(wl + k * HH + 256 + cg * 4); // contiguous b128
      float av[8] = {a0.x, a0.y, a0.z, a0.w, a1.x, a1.y, a1.z, a1.w};
      f2 bv[4] = {{b0.x, b0.y}, {b0.z, b0.w}, {b1v.x, b1v.y}, {b1v.z, b1v.w}};
#pragma unroll
      for (int i = 0; i < 8; ++i) {
        f2 ai = {av[i], av[i]};
#pragma unroll
        for (int j = 0; j < 4; ++j) {
          f2 pr = ai * bv[j];                 // v_pk_mul_f32 (no contract)
          acc[i][j] = acc[i][j] + pr;         // v_pk_add_f32
        }
      }
    }
  }
  __syncthreads();   // staging done; smem becomes hs

  float sum[4] = {0.f, 0.f, 0.f, 0.f};

  // ---- phase A: h cols 0..255 ----
  {
    const int c0 = cg * 4;
#pragma unroll
    for (int i = 0; i < 8; ++i) {
      int r = rg * 8 + i;
      float4 hv;
      hv.x = xla_tanh_f32(acc[i][0].x + b1[c0 + 0]);
      hv.y = xla_tanh_f32(acc[i][0].y + b1[c0 + 1]);
      hv.z = xla_tanh_f32(acc[i][1].x + b1[c0 + 2]);
      hv.w = xla_tanh_f32(acc[i][1].y + b1[c0 + 3]);
      *(float4*)(hs + r * 260 + c0) = hv;
    }
  }
  __syncthreads();
#pragma unroll
  for (int it = 0; it < 4; ++it) {
    int idx = tid + it * 512;
    if (idx < 64 * TAGS) {
      int r = idx & 63, c = idx >> 6;        // c wave-uniform -> W2 scalarizes
      float s = 0.f;
#pragma unroll 4
      for (int k4 = 0; k4 < 64; ++k4) {
        float4 h4 = *(float4*)(hs + r * 260 + k4 * 4);
        float p0 = h4.x * W2[(k4 * 4 + 0) * TAGS + c]; s = s + p0;
        float p1 = h4.y * W2[(k4 * 4 + 1) * TAGS + c]; s = s + p1;
        float p2 = h4.z * W2[(k4 * 4 + 2) * TAGS + c]; s = s + p2;
        float p3 = h4.w * W2[(k4 * 4 + 3) * TAGS + c]; s = s + p3;
      }
      sum[it] = s;
    }
  }
  __syncthreads();

  // ---- phase B: h cols 256..511 ----
  {
    const int c0 = cg * 4;                   // global col = 256 + c0
#pragma unroll
    for (int i = 0; i < 8; ++i) {
      int r = rg * 8 + i;
      float4 hv;
      hv.x = xla_tanh_f32(acc[i][2].x + b1[256 + c0 + 0]);
      hv.y = xla_tanh_f32(acc[i][2].y + b1[256 + c0 + 1]);
      hv.z = xla_tanh_f32(acc[i][3].x + b1[256 + c0 + 2]);
      hv.w = xla_tanh_f32(acc[i][3].y + b1[256 + c0 + 3]);
      *(float4*)(hs + r * 260 + c0) = hv;
    }
  }
  __syncthreads();
#pragma unroll
  for (int it = 0; it < 4; ++it) {
    int idx = tid + it * 512;
    if (idx < 64 * TAGS) {
      int r = idx & 63, c = idx >> 6;
      float s = sum[it];
#pragma unroll 4
      for (int k4 = 0; k4 < 64; ++k4) {
        float4 h4 = *(float4*)(hs + r * 260 + k4 * 4);
        float p0 = h4.x * W2[(256 + k4 * 4 + 0) * TAGS + c]; s = s + p0;
        float p1 = h4.y * W2[(256 + k4 * 4 + 1) * TAGS + c]; s = s + p1;
        float p2 = h4.z * W2[(256 + k4 * 4 + 2) * TAGS + c]; s = s + p2;
        float p3 = h4.w * W2[(256 + k4 * 4 + 3) * TAGS + c]; s = s + p3;
      }
      feats[(size_t)(row0 + r) * FSTRIDE + c] = s + b2[c];
    }
  }
}

// ---------------------------------------------------------------------------
// Kernel 2: top-1 Viterbi (== nbest[...,0], proven). 1 wave per b; lane=to.
// part broadcast via LDS (1 ds_write + 8 broadcast b128 reads), then
// adjacent-pair tournament: exact lowest-index-on-tie argmax, same fp adds
// in reference op order (f + trans) + part.
// ---------------------------------------------------------------------------
__global__ __launch_bounds__(64) void viterbi_kernel(
    const float* __restrict__ feats, const float* __restrict__ trans,
    int* __restrict__ out)
{
#pragma clang fp contract(off)
  const int b = blockIdx.x;
  const int lane = threadIdx.x;
  const bool act = lane < TAGS;
  __shared__ unsigned char bp[LL][32];     // 32 KB
  __shared__ __align__(16) float pbuf[32];

  float tr[TAGS];
  const int tl = act ? lane : 0;
#pragma unroll
  for (int f = 0; f < TAGS; ++f) tr[f] = trans[f * TAGS + tl];

  const float* frow = feats + (size_t)b * LL * FSTRIDE;
  float part = act ? (frow[lane] + tr[START_TAG]) : -3.0e38f;
  if (lane >= TAGS && lane < 32) pbuf[lane] = -3.0e38f;

  float fc[8], fn[8];
#pragma unroll
  for (int d = 0; d < 8; ++d) fc[d] = act ? frow[(1 + d) * FSTRIDE + lane] : 0.f;

  for (int t0 = 1; t0 < LL; t0 += 8) {
#pragma unroll
    for (int d = 0; d < 8; ++d) {
      int t = t0 + 8 + d;
      fn[d] = (act && t < LL) ? frow[t * FSTRIDE + lane] : 0.f;
    }
#pragma unroll
    for (int d = 0; d < 8; ++d) {
      int t = t0 + d;
      if (t < LL) {
        if (act) pbuf[lane] = part;          // same-wave LDS: in-order
        float4 s0 = *(float4*)(pbuf + 0);    // broadcast reads (no conflict)
        float4 s1 = *(float4*)(pbuf + 4);
        float4 s2 = *(float4*)(pbuf + 8);
        float4 s3 = *(float4*)(pbuf + 12);
        float4 s4 = *(float4*)(pbuf + 16);
        float4 s5 = *(float4*)(pbuf + 20);
        float4 s6 = *(float4*)(pbuf + 24);
        float4 s7 = *(float4*)(pbuf + 28);
        float sv[32] = {s0.x, s0.y, s0.z, s0.w, s1.x, s1.y, s1.z, s1.w,
                        s2.x, s2.y, s2.z, s2.w, s3.x, s3.y, s3.z, s3.w,
                        s4.x, s4.y, s4.z, s4.w, s5.x, s5.y, s5.z, s5.w,
                        s6.x, s6.y, s6.z, s6.w, s7.x, s7.y, s7.z, s7.w};
        float fv = fc[d];
        float v[32];
#pragma unroll
        for (int fr = 0; fr < TAGS; ++fr)
          v[fr] = (fv + tr[fr]) + sv[fr];    // reference op order
#pragma unroll
        for (int fr = TAGS; fr < 32; ++fr) v[fr] = -3.0e38f;

        // adjacent-pair tournament: lowest index wins ties (== strict '>'
        // ascending scan). 32 -> 16 -> 8 -> 4 -> 2 -> 1.
        float tv[16]; int ti[16];
#pragma unroll
        for (int i = 0; i < 16; ++i) {
          bool w = v[2 * i + 1] > v[2 * i];
          tv[i] = w ? v[2 * i + 1] : v[2 * i];
          ti[i] = w ? 2 * i + 1 : 2 * i;
        }
#pragma unroll
        for (int i = 0; i < 8; ++i) {
          bool w = tv[2 * i + 1] > tv[2 * i];
          tv[i] = w ? tv[2 * i + 1] : tv[2 * i];
          ti[i] = w ? ti[2 * i + 1] : ti[2 * i];
        }
#pragma unroll
        for (int i = 0; i < 4; ++i) {
          bool w = tv[2 * i + 1] > tv[2 * i];
          tv[i] = w ? tv[2 * i + 1] : tv[2 * i];
          ti[i] = w ? ti[2 * i + 1] : ti[2 * i];
        }
#pragma unroll
        for (int i = 0; i < 2; ++i) {
          bool w = tv[2 * i + 1] > tv[2 * i];
          tv[i] = w ? tv[2 * i + 1] : tv[2 * i];
          ti[i] = w ? ti[2 * i + 1] : ti[2 * i];
        }
        {
          bool w = tv[1] > tv[0];
          part = w ? tv[1] : tv[0];
          int bi = w ? ti[1] : ti[0];
          if (act) bp[t][lane] = (unsigned char)bi;
        }
      }
    }
#pragma unroll
    for (int d = 0; d < 8; ++d) fc[d] = fn[d];
  }

  // final transition into STOP, lowest-from tie-break (once; serial scan ok)
  float best = -3.0e38f;
  int p0 = 0;
#pragma unroll
  for (int fr = 0; fr < TAGS; ++fr) {
    float s = __shfl(part, fr, 64);
    float v = s + trans[fr * TAGS + STOP_TAG];
    if (v > best) { best = v; p0 = fr; }
  }

  __syncthreads();
  if (lane == 0) {
    int* ob = out + (size_t)b * LL;
    int p = p0;
    ob[LL - 1] = p;
    for (int t = LL - 1; t >= 1; --t) {
      p = bp[t][p];
      ob[t - 1] = p;
    }
  }
}

// ---------------------------------------------------------------------------
extern "C" void kernel_launch(void* const* d_in, const int* in_sizes, int n_in,
                              void* d_out, int out_size, void* d_ws, size_t ws_size,
                              hipStream_t stream) {
  const float* X  = (const float*)d_in[0];
  const float* W1 = (const float*)d_in[2];
  const float* b1 = (const float*)d_in[3];
  const float* W2 = (const float*)d_in[4];
  const float* b2 = (const float*)d_in[5];
  const float* tr = (const float*)d_in[6];

  float* feats = (float*)d_ws;          // (B*L) x 32 padded fp32 rows = 8 MB
  int* out = (int*)d_out;

  mlp_kernel<<<dim3(BB * LL / 64), dim3(512), 0, stream>>>(X, W1, b1, W2, b2, feats);
  viterbi_kernel<<<dim3(BB), dim3(64), 0, stream>>>(feats, tr, out);
}